// Round 1
// baseline (924.894 us; speedup 1.0000x reference)
//
#include <hip/hip_runtime.h>

// LSTM anomaly detector: B=4096, T=512, I=3, H=64 (4H=256 gates)
// One block = 16 batch rows, 4 waves. Wave w owns gate columns [w*64, w*64+64).
// Recurrent matmul via mfma_f32_16x16x32_bf16 with hi/lo bf16 split (fp32-grade).
// W_hh/W_ih/bias/W_dec live in registers as pre-split B-fragments.

#define TLEN 512
#define TCHUNK 64

typedef float  float4_t __attribute__((ext_vector_type(4)));
typedef __bf16 bf16x8   __attribute__((ext_vector_type(8)));

__device__ __forceinline__ float fexp2(float x){ return __builtin_amdgcn_exp2f(x); }
__device__ __forceinline__ float frcp (float x){ return __builtin_amdgcn_rcpf(x); }
__device__ __forceinline__ float sigm (float x){ return frcp(1.f + fexp2(-1.44269504f*x)); }
__device__ __forceinline__ float tanh_(float x){ return 1.f - 2.f*frcp(1.f + fexp2(2.88539008f*x)); }

// split 8 fp32 into hi/lo bf16 fragments (RNE): v ~= hi + lo with ~2^-17 rel err
__device__ __forceinline__ void split8(const float* v, bf16x8& hi, bf16x8& lo){
  #pragma unroll
  for (int j = 0; j < 8; j++){
    __bf16 h = (__bf16)v[j];
    hi[j] = h;
    lo[j] = (__bf16)(v[j] - (float)h);
  }
}

#define MFMA(a,b,c) __builtin_amdgcn_mfma_f32_16x16x32_bf16((a),(b),(c),0,0,0)

// LDS layout (floats), padded to avoid bank conflicts
#define ACT 0        // [4 types][16 rows][66]  (stride 66 breaks 4-way)
#define HOF 4224     // [16 rows][68]           (stride 68: b128 reads balanced)
#define XOF 5312     // [16 rows][196]          (192 used, pad keeps 16B align + bank offset)
#define OOF 8448     // [16 rows][196]
#define LDSZ 11584

__global__ __launch_bounds__(256, 1)
void LSTMAnomalyDetector_kernel(
    const float* __restrict__ x,     const float* __restrict__ W_ih,
    const float* __restrict__ W_hh,  const float* __restrict__ b_ih,
    const float* __restrict__ b_hh,  const float* __restrict__ W_dec,
    const float* __restrict__ b_dec, float* __restrict__ out)
{
  __shared__ float L[LDSZ];

  const int tid  = threadIdx.x;
  const int w    = tid >> 6;        // wave 0..3  (= gate type i,f,g,o)
  const int lane = tid & 63;
  const int q    = lane >> 4;       // quad 0..3
  const int lid  = lane & 15;
  const int b0   = blockIdx.x * 16; // batch rows [b0, b0+16)

  // ---- resident weight fragments (B-operand: B[k=q*8+j][n=lid]) ----
  bf16x8 Bh[4][2], Bl[4][2];  // W_hh^T  : 4 N-tiles x 2 K-tiles, hi/lo
  bf16x8 Xh[4],    Xl[4];     // x-tile  : rows k=0..2 -> W_ih, k=3 -> b_ih+b_hh
  bf16x8 Dh[2],    Dl[2];     // decoder : W_dec^T (cols 0..2 valid)

  #pragma unroll
  for (int tl = 0; tl < 4; tl++){
    const int g = w*64 + tl*16 + lid;           // global gate row (row-major W_hh[256][64])
    #pragma unroll
    for (int kt = 0; kt < 2; kt++){
      const float* p = W_hh + g*64 + kt*32 + q*8;
      float v[8];
      #pragma unroll
      for (int j = 0; j < 8; j++) v[j] = p[j];
      split8(v, Bh[tl][kt], Bl[tl][kt]);
    }
    float v[8] = {0.f,0.f,0.f,0.f,0.f,0.f,0.f,0.f};
    if (q == 0){
      v[0] = W_ih[g*3+0]; v[1] = W_ih[g*3+1]; v[2] = W_ih[g*3+2];
      v[3] = b_ih[g] + b_hh[g];
    }
    split8(v, Xh[tl], Xl[tl]);
  }
  #pragma unroll
  for (int kt = 0; kt < 2; kt++){
    float v[8] = {0.f,0.f,0.f,0.f,0.f,0.f,0.f,0.f};
    if (lid < 3){
      const float* p = W_dec + lid*64 + kt*32 + q*8;
      #pragma unroll
      for (int j = 0; j < 8; j++) v[j] = p[j];
    }
    split8(v, Dh[kt], Dl[kt]);
  }
  const float bdec = (lid < 3) ? b_dec[lid] : 0.f;

  // ---- state ----
  bf16x8 ah[2], al[2];                       // A-fragments of h (hi/lo), h0 = 0
  { float z[8] = {0.f,0.f,0.f,0.f,0.f,0.f,0.f,0.f};
    split8(z, ah[0], al[0]); split8(z, ah[1], al[1]); }
  float creg[4] = {0.f, 0.f, 0.f, 0.f};      // c for rows m = w*4 + r, col j = lane

  // ---- preload x chunk 0 (coalesced: 768 float4 over 256 threads) ----
  #pragma unroll
  for (int s = 0; s < 3; s++){
    const int f = tid + 256*s; const int row = f/48; const int off = (f%48)*4;
    float4_t v = *(const float4_t*)(x + (size_t)(b0+row)*1536 + off);
    *(float4_t*)&L[XOF + row*196 + off] = v;
  }
  __syncthreads();

  for (int t = 0; t < TLEN; ++t){
    const int dt = t & (TCHUNK-1);

    // x A-fragment: A[m=lid][k] = {x0,x1,x2,1,0...} for quad 0, zeros elsewhere
    float xv[8] = {0.f,0.f,0.f,0.f,0.f,0.f,0.f,0.f};
    if (q == 0){
      const float* xp = &L[XOF + lid*196 + dt*3];
      xv[0] = xp[0]; xv[1] = xp[1]; xv[2] = xp[2]; xv[3] = 1.0f;
    }
    bf16x8 xah, xal; split8(xv, xah, xal);

    // gate preacts: C[m][g] = h@W_hh^T + x@W_ih^T + bias   (hi/lo split: 3 mfma/product)
    #pragma unroll
    for (int tl = 0; tl < 4; tl++){
      float4_t acc = {0.f,0.f,0.f,0.f};
      acc = MFMA(ah[0], Bh[tl][0], acc);
      acc = MFMA(ah[1], Bh[tl][1], acc);
      acc = MFMA(al[0], Bh[tl][0], acc);
      acc = MFMA(al[1], Bh[tl][1], acc);
      acc = MFMA(ah[0], Bl[tl][0], acc);
      acc = MFMA(ah[1], Bl[tl][1], acc);
      acc = MFMA(xah,   Xh[tl],    acc);
      acc = MFMA(xal,   Xh[tl],    acc);
      acc = MFMA(xah,   Xl[tl],    acc);
      // activation (wave-uniform branch) + stage to LDS: C layout col=lid, row=q*4+r
      #pragma unroll
      for (int r = 0; r < 4; r++){
        const float a = (w == 2) ? tanh_(acc[r]) : sigm(acc[r]);
        L[ACT + w*1056 + (q*4+r)*66 + tl*16 + lid] = a;
      }
    }
    __syncthreads();

    // c/h update: thread owns (m = w*4+r, j = lane)
    float hnew[4];
    #pragma unroll
    for (int r = 0; r < 4; r++){
      const int m = w*4 + r;
      const float ig = L[ACT +        m*66 + lane];
      const float fg = L[ACT + 1056 + m*66 + lane];
      const float gg = L[ACT + 2112 + m*66 + lane];
      const float og = L[ACT + 3168 + m*66 + lane];
      creg[r] = fg*creg[r] + ig*gg;
      hnew[r] = og * tanh_(creg[r]);
    }
    #pragma unroll
    for (int r = 0; r < 4; r++) L[HOF + (w*4+r)*68 + lane] = hnew[r];
    __syncthreads();

    // rebuild h A-fragments: A[m=lid][k = kt*32 + q*8 + j]
    #pragma unroll
    for (int kt = 0; kt < 2; kt++){
      const float4_t* hp = (const float4_t*)&L[HOF + lid*68 + kt*32 + q*8];
      const float4_t h0 = hp[0], h1 = hp[1];
      float v[8] = {h0.x,h0.y,h0.z,h0.w,h1.x,h1.y,h1.z,h1.w};
      split8(v, ah[kt], al[kt]);
    }

    // decoder on wave 3: out[m][o] = h_t @ W_dec^T + b_dec, staged to LDS
    if (w == 3){
      float4_t d = {0.f,0.f,0.f,0.f};
      d = MFMA(ah[0], Dh[0], d);
      d = MFMA(ah[1], Dh[1], d);
      d = MFMA(al[0], Dh[0], d);
      d = MFMA(al[1], Dh[1], d);
      d = MFMA(ah[0], Dl[0], d);
      d = MFMA(ah[1], Dl[1], d);
      if (lid < 3){
        #pragma unroll
        for (int r = 0; r < 4; r++)
          L[OOF + (q*4+r)*196 + dt*3 + lid] = d[r] + bdec;
      }
    }

    // chunk boundary: flush out, load next x chunk (both coalesced float4)
    if (dt == TCHUNK-1){
      __syncthreads();
      const int t0 = t - (TCHUNK-1);
      #pragma unroll
      for (int s = 0; s < 3; s++){
        const int f = tid + 256*s; const int row = f/48; const int off = (f%48)*4;
        float4_t v = *(const float4_t*)&L[OOF + row*196 + off];
        *(float4_t*)(out + (size_t)(b0+row)*1536 + t0*3 + off) = v;
      }
      if (t + 1 < TLEN){
        #pragma unroll
        for (int s = 0; s < 3; s++){
          const int f = tid + 256*s; const int row = f/48; const int off = (f%48)*4;
          float4_t v = *(const float4_t*)(x + (size_t)(b0+row)*1536 + (t+1)*3 + off);
          *(float4_t*)&L[XOF + row*196 + off] = v;
        }
      }
      __syncthreads();
    }
  }
}

extern "C" void kernel_launch(void* const* d_in, const int* in_sizes, int n_in,
                              void* d_out, int out_size, void* d_ws, size_t ws_size,
                              hipStream_t stream)
{
  const float* x     = (const float*)d_in[0];
  const float* W_ih  = (const float*)d_in[1];
  const float* W_hh  = (const float*)d_in[2];
  const float* b_ih  = (const float*)d_in[3];
  const float* b_hh  = (const float*)d_in[4];
  const float* W_dec = (const float*)d_in[5];
  const float* b_dec = (const float*)d_in[6];
  float* out = (float*)d_out;

  const int B = in_sizes[0] / (TLEN * 3);   // 4096
  const int blocks = B / 16;                // 256
  hipLaunchKernelGGL(LSTMAnomalyDetector_kernel, dim3(blocks), dim3(256), 0, stream,
                     x, W_ih, W_hh, b_ih, b_hh, W_dec, b_dec, out);
}

// Round 2
// 567.685 us; speedup vs baseline: 1.6292x; 1.6292x over previous
//
#include <hip/hip_runtime.h>

// LSTM anomaly detector: B=4096, T=512, I=3, H=64 (4H=256 gates)
// One block = 16 batch rows, 4 waves, grid=256 (1 block/CU).
// Re-tiled so wave w owns cols [w*16, w*16+16) of ALL FOUR gates:
// after its 4 tile-MFMAs a lane holds i,f,g,o for (row=q*4+r, col=w*16+lid)
// in registers -> activations + c/h update are lane-local (no ACT LDS, 1 barrier/step).
// h A-fragment rebuild: double-buffered LDS (t-parity) so one barrier suffices.
// Recurrent matmul via mfma_f32_16x16x32_bf16 with hi/lo bf16 split (fp32-grade).

#define TLEN 512
#define TCHUNK 64

typedef float  float4_t __attribute__((ext_vector_type(4)));
typedef __bf16 bf16x8   __attribute__((ext_vector_type(8)));

__device__ __forceinline__ float fexp2(float x){ return __builtin_amdgcn_exp2f(x); }
__device__ __forceinline__ float frcp (float x){ return __builtin_amdgcn_rcpf(x); }
__device__ __forceinline__ float sigm (float x){ return frcp(1.f + fexp2(-1.44269504f*x)); }
__device__ __forceinline__ float tanh_(float x){ return 1.f - 2.f*frcp(1.f + fexp2(2.88539008f*x)); }

// split 8 fp32 into hi/lo bf16 fragments (RNE): v ~= hi + lo with ~2^-17 rel err
__device__ __forceinline__ void split8(const float* v, bf16x8& hi, bf16x8& lo){
  #pragma unroll
  for (int j = 0; j < 8; j++){
    __bf16 h = (__bf16)v[j];
    hi[j] = h;
    lo[j] = (__bf16)(v[j] - (float)h);
  }
}

#define MFMA(a,b,c) __builtin_amdgcn_mfma_f32_16x16x32_bf16((a),(b),(c),0,0,0)

// LDS layout (floats)
#define HOF 0        // 2 x [16 rows][68]  double-buffered h (stride 68)
#define XOF 2176     // [16 rows][196]     x chunk (192 used)
#define OOF 5312     // [16 rows][196]     out chunk
#define LDSZ 8448

__global__ __launch_bounds__(256, 1)
void LSTMAnomalyDetector_kernel(
    const float* __restrict__ x,     const float* __restrict__ W_ih,
    const float* __restrict__ W_hh,  const float* __restrict__ b_ih,
    const float* __restrict__ b_hh,  const float* __restrict__ W_dec,
    const float* __restrict__ b_dec, float* __restrict__ out)
{
  __shared__ float L[LDSZ];

  const int tid  = threadIdx.x;
  const int w    = tid >> 6;        // wave 0..3 (owns cols w*16..w*16+15 of every gate)
  const int lane = tid & 63;
  const int q    = lane >> 4;       // quad 0..3
  const int lid  = lane & 15;
  const int b0   = blockIdx.x * 16; // batch rows [b0, b0+16)

  // ---- resident weight fragments (B-operand: B[k=kt*32+q*8+j][n=lid]) ----
  // tl = gate type (0:i 1:f 2:g 3:o); gate row = tl*64 + w*16 + lid
  bf16x8 Bh[4][2], Bl[4][2];  // W_hh^T  hi/lo
  bf16x8 Xh[4],    Xl[4];     // x-tile: rows k=0..2 -> W_ih, k=3 -> b_ih+b_hh
  bf16x8 Dh[2],    Dl[2];     // decoder: W_dec^T (cols 0..2 valid)

  #pragma unroll
  for (int tl = 0; tl < 4; tl++){
    const int g = tl*64 + w*16 + lid;           // global gate row (W_hh[256][64] row-major)
    #pragma unroll
    for (int kt = 0; kt < 2; kt++){
      const float* p = W_hh + g*64 + kt*32 + q*8;
      float v[8];
      #pragma unroll
      for (int j = 0; j < 8; j++) v[j] = p[j];
      split8(v, Bh[tl][kt], Bl[tl][kt]);
    }
    float v[8] = {0.f,0.f,0.f,0.f,0.f,0.f,0.f,0.f};
    if (q == 0){
      v[0] = W_ih[g*3+0]; v[1] = W_ih[g*3+1]; v[2] = W_ih[g*3+2];
      v[3] = b_ih[g] + b_hh[g];
    }
    split8(v, Xh[tl], Xl[tl]);
  }
  #pragma unroll
  for (int kt = 0; kt < 2; kt++){
    float v[8] = {0.f,0.f,0.f,0.f,0.f,0.f,0.f,0.f};
    if (lid < 3){
      const float* p = W_dec + lid*64 + kt*32 + q*8;
      #pragma unroll
      for (int j = 0; j < 8; j++) v[j] = p[j];
    }
    split8(v, Dh[kt], Dl[kt]);
  }
  const float bdec = (lid < 3) ? b_dec[lid] : 0.f;

  // ---- state ----
  bf16x8 ah[2], al[2];                       // A-fragments of h_{t-1} (hi/lo), h_{-1}=0
  { float z[8] = {0.f,0.f,0.f,0.f,0.f,0.f,0.f,0.f};
    split8(z, ah[0], al[0]); split8(z, ah[1], al[1]); }
  float creg[4] = {0.f, 0.f, 0.f, 0.f};      // c for (row q*4+r, col w*16+lid)

  // ---- preload x chunk 0 (coalesced: 768 float4 over 256 threads) ----
  #pragma unroll
  for (int s = 0; s < 3; s++){
    const int f = tid + 256*s; const int row = f/48; const int off = (f%48)*4;
    float4_t v = *(const float4_t*)(x + (size_t)(b0+row)*1536 + off);
    *(float4_t*)&L[XOF + row*196 + off] = v;
  }
  __syncthreads();

  for (int t = 0; t < TLEN; ++t){
    const int dt   = t & (TCHUNK-1);
    const int hbuf = HOF + (t & 1) * 1088;

    // x A-fragment: A[m=lid][k] = {x0,x1,x2,1,0...} on quad 0, zeros elsewhere
    float xv[8] = {0.f,0.f,0.f,0.f,0.f,0.f,0.f,0.f};
    if (q == 0){
      const float* xp = &L[XOF + lid*196 + dt*3];
      xv[0] = xp[0]; xv[1] = xp[1]; xv[2] = xp[2]; xv[3] = 1.0f;
    }
    bf16x8 xah, xal; split8(xv, xah, xal);

    // gate preacts: lane gets all 4 gate types for (rows q*4+r, col w*16+lid).
    // Two accumulator chains per tile (depth 4/5) for MFMA-latency overlap.
    float4_t g4[4];
    #pragma unroll
    for (int tl = 0; tl < 4; tl++){
      float4_t accA = {0.f,0.f,0.f,0.f};
      float4_t accB = {0.f,0.f,0.f,0.f};
      accA = MFMA(ah[0], Bh[tl][0], accA);
      accA = MFMA(ah[1], Bh[tl][1], accA);
      accA = MFMA(al[0], Bh[tl][0], accA);
      accA = MFMA(al[1], Bh[tl][1], accA);
      accB = MFMA(ah[0], Bl[tl][0], accB);
      accB = MFMA(ah[1], Bl[tl][1], accB);
      accB = MFMA(xah,   Xh[tl],    accB);
      accB = MFMA(xal,   Xh[tl],    accB);
      accB = MFMA(xah,   Xl[tl],    accB);
      g4[tl] = accA + accB;
    }

    // lane-local activations + c/h update; write h_t to double-buffered LDS
    #pragma unroll
    for (int r = 0; r < 4; r++){
      const float ig = sigm (g4[0][r]);
      const float fg = sigm (g4[1][r]);
      const float gg = tanh_(g4[2][r]);
      const float og = sigm (g4[3][r]);
      creg[r] = fg*creg[r] + ig*gg;
      const float h = og * tanh_(creg[r]);
      L[hbuf + (q*4+r)*68 + w*16 + lid] = h;   // 2-way bank alias only (free)
    }
    __syncthreads();   // the ONE barrier per step

    // rebuild h A-fragments: A[m=lid][k = kt*32 + q*8 + j]
    #pragma unroll
    for (int kt = 0; kt < 2; kt++){
      const float4_t* hp = (const float4_t*)&L[hbuf + lid*68 + kt*32 + q*8];
      const float4_t h0 = hp[0], h1 = hp[1];
      float v[8] = {h0.x,h0.y,h0.z,h0.w,h1.x,h1.y,h1.z,h1.w};
      split8(v, ah[kt], al[kt]);
    }

    // decoder on wave 0 (every wave holds full h A-frag): out_t = h_t@W_dec^T + b
    if (w == 0){
      float4_t d = {0.f,0.f,0.f,0.f};
      d = MFMA(ah[0], Dh[0], d);
      d = MFMA(ah[1], Dh[1], d);
      d = MFMA(al[0], Dh[0], d);
      d = MFMA(al[1], Dh[1], d);
      d = MFMA(ah[0], Dl[0], d);
      d = MFMA(ah[1], Dl[1], d);
      if (lid < 3){
        #pragma unroll
        for (int r = 0; r < 4; r++)
          L[OOF + (q*4+r)*196 + dt*3 + lid] = d[r] + bdec;
      }
    }

    // chunk boundary: flush out, load next x chunk (both coalesced float4)
    if (dt == TCHUNK-1){
      __syncthreads();
      const int t0 = t - (TCHUNK-1);
      #pragma unroll
      for (int s = 0; s < 3; s++){
        const int f = tid + 256*s; const int row = f/48; const int off = (f%48)*4;
        float4_t v = *(const float4_t*)&L[OOF + row*196 + off];
        *(float4_t*)(out + (size_t)(b0+row)*1536 + t0*3 + off) = v;
      }
      if (t + 1 < TLEN){
        #pragma unroll
        for (int s = 0; s < 3; s++){
          const int f = tid + 256*s; const int row = f/48; const int off = (f%48)*4;
          float4_t v = *(const float4_t*)(x + (size_t)(b0+row)*1536 + (t+1)*3 + off);
          *(float4_t*)&L[XOF + row*196 + off] = v;
        }
      }
      __syncthreads();
    }
  }
}

extern "C" void kernel_launch(void* const* d_in, const int* in_sizes, int n_in,
                              void* d_out, int out_size, void* d_ws, size_t ws_size,
                              hipStream_t stream)
{
  const float* x     = (const float*)d_in[0];
  const float* W_ih  = (const float*)d_in[1];
  const float* W_hh  = (const float*)d_in[2];
  const float* b_ih  = (const float*)d_in[3];
  const float* b_hh  = (const float*)d_in[4];
  const float* W_dec = (const float*)d_in[5];
  const float* b_dec = (const float*)d_in[6];
  float* out = (float*)d_out;

  const int B = in_sizes[0] / (TLEN * 3);   // 4096
  const int blocks = B / 16;                // 256
  hipLaunchKernelGGL(LSTMAnomalyDetector_kernel, dim3(blocks), dim3(256), 0, stream,
                     x, W_ih, W_hh, b_ih, b_hh, W_dec, b_dec, out);
}

// Round 3
// 529.791 us; speedup vs baseline: 1.7458x; 1.0715x over previous
//
#include <hip/hip_runtime.h>

// LSTM anomaly detector: B=4096, T=512, I=3, H=64 (4H=256 gates)
// One block = 16 batch rows, 4 waves, grid=256 (1 block/CU).
// Wave w owns cols [w*16,w*16+16) of all four gates -> lane-local i,f,g,o.
// NEW (R3): all bf16 hi/lo splitting moved OFF the per-step critical path:
//  - h is split by the PRODUCER with bit tricks (trunc-split, exact to 2^-16)
//    into two bf16 LDS arrays; consumer rebuilds A-frags with 4 ds_read_b128
//    and ZERO VALU.
//  - x is pre-packed once per 64-step chunk into bf16x4 hi/lo records
//    [x0,x1,x2,1.0]; per-step x-frag = 2 ds_read_b64 + cndmask.

#define TLEN 512
#define TCHUNK 64

typedef float  float4_t __attribute__((ext_vector_type(4)));
typedef __bf16 bf16x8   __attribute__((ext_vector_type(8)));
typedef unsigned int uint2_t __attribute__((ext_vector_type(2)));

__device__ __forceinline__ float fexp2(float x){ return __builtin_amdgcn_exp2f(x); }
__device__ __forceinline__ float frcp (float x){ return __builtin_amdgcn_rcpf(x); }
__device__ __forceinline__ float sigm (float x){ return frcp(1.f + fexp2(-1.44269504f*x)); }
__device__ __forceinline__ float tanh_(float x){ return 1.f - 2.f*frcp(1.f + fexp2(2.88539008f*x)); }

// setup-only RNE split (weights; cost irrelevant)
__device__ __forceinline__ void split8(const float* v, bf16x8& hi, bf16x8& lo){
  #pragma unroll
  for (int j = 0; j < 8; j++){
    __bf16 h = (__bf16)v[j];
    hi[j] = h;
    lo[j] = (__bf16)(v[j] - (float)h);
  }
}

#define MFMA(a,b,c) __builtin_amdgcn_mfma_f32_16x16x32_bf16((a),(b),(c),0,0,0)

// ---- LDS layout ----
// ushort region (bf16):
#define HHI 0        // 2 x [16 rows][72]  (double-buffered, stride 72 -> 16B rows)
#define HLO 2304
#define XPH 4608     // [64 t][16 rows][4] packed {x0,x1,x2,1.0} hi
#define XPL 8704     // same, lo ({x0,x1,x2,0})
#define HS_SZ 12800
// float region:
#define XOF 0        // [16 rows][196] fp32 x staging
#define OOF 3136     // [16 rows][196] fp32 out staging
#define LF_SZ 6272

__global__ __launch_bounds__(256, 1)
void LSTMAnomalyDetector_kernel(
    const float* __restrict__ x,     const float* __restrict__ W_ih,
    const float* __restrict__ W_hh,  const float* __restrict__ b_ih,
    const float* __restrict__ b_hh,  const float* __restrict__ W_dec,
    const float* __restrict__ b_dec, float* __restrict__ out)
{
  __shared__ __align__(16) unsigned short HS[HS_SZ];
  __shared__ __align__(16) float          LF[LF_SZ];

  const int tid  = threadIdx.x;
  const int w    = tid >> 6;        // wave 0..3
  const int lane = tid & 63;
  const int q    = lane >> 4;       // quad 0..3
  const int lid  = lane & 15;
  const int b0   = blockIdx.x * 16; // batch rows [b0, b0+16)
  const int cw   = w*16 + lid;      // this lane's H-column

  // ---- resident weight fragments (B-operand: B[k=kt*32+q*8+j][n=lid]) ----
  bf16x8 Bh[4][2], Bl[4][2];  // W_hh^T hi/lo; tl = gate type (i,f,g,o)
  bf16x8 Xh[4],    Xl[4];     // x-tile: k=0..2 -> W_ih, k=3 -> b_ih+b_hh
  bf16x8 Dh[2],    Dl[2];     // decoder: W_dec^T (cols 0..2 valid)

  #pragma unroll
  for (int tl = 0; tl < 4; tl++){
    const int g = tl*64 + cw;                   // gate row (W_hh[256][64] row-major)
    #pragma unroll
    for (int kt = 0; kt < 2; kt++){
      const float* p = W_hh + g*64 + kt*32 + q*8;
      float v[8];
      #pragma unroll
      for (int j = 0; j < 8; j++) v[j] = p[j];
      split8(v, Bh[tl][kt], Bl[tl][kt]);
    }
    float v[8] = {0.f,0.f,0.f,0.f,0.f,0.f,0.f,0.f};
    if (q == 0){
      v[0] = W_ih[g*3+0]; v[1] = W_ih[g*3+1]; v[2] = W_ih[g*3+2];
      v[3] = b_ih[g] + b_hh[g];
    }
    split8(v, Xh[tl], Xl[tl]);
  }
  #pragma unroll
  for (int kt = 0; kt < 2; kt++){
    float v[8] = {0.f,0.f,0.f,0.f,0.f,0.f,0.f,0.f};
    if (lid < 3){
      const float* p = W_dec + lid*64 + kt*32 + q*8;
      #pragma unroll
      for (int j = 0; j < 8; j++) v[j] = p[j];
    }
    split8(v, Dh[kt], Dl[kt]);
  }
  const float bdec = (lid < 3) ? b_dec[lid] : 0.f;

  // ---- state ----
  bf16x8 ah[2] = {}, al[2] = {};             // A-frags of h_{t-1} (hi/lo); h_{-1}=0
  float creg[4] = {0.f, 0.f, 0.f, 0.f};      // c for (row q*4+r, col cw)

  // ---- preload + pack x chunk 0 ----
  #pragma unroll
  for (int s = 0; s < 3; s++){
    const int f = tid + 256*s; const int row = f/48; const int off = (f%48)*4;
    float4_t v = *(const float4_t*)(x + (size_t)(b0+row)*1536 + off);
    *(float4_t*)&LF[XOF + row*196 + off] = v;
  }
  __syncthreads();
  #pragma unroll
  for (int s = 0; s < 4; s++){
    const int p = tid + 256*s;                 // (t,row) pair: t=p>>4, row=p&15
    const float* xp = &LF[XOF + (p & 15)*196 + (p >> 4)*3];
    const unsigned u0 = __float_as_uint(xp[0]);
    const unsigned u1 = __float_as_uint(xp[1]);
    const unsigned u2 = __float_as_uint(xp[2]);
    const float l0 = xp[0] - __uint_as_float(u0 & 0xFFFF0000u);
    const float l1 = xp[1] - __uint_as_float(u1 & 0xFFFF0000u);
    const float l2 = xp[2] - __uint_as_float(u2 & 0xFFFF0000u);
    uint2_t hi, lo;
    hi[0] = (u0 >> 16) | (u1 & 0xFFFF0000u);
    hi[1] = (u2 >> 16) | 0x3F800000u;          // bf16(1.0) in k=3
    lo[0] = (__float_as_uint(l0) >> 16) | (__float_as_uint(l1) & 0xFFFF0000u);
    lo[1] = (__float_as_uint(l2) >> 16);
    *(uint2_t*)&HS[XPH + p*4] = hi;
    *(uint2_t*)&HS[XPL + p*4] = lo;
  }
  __syncthreads();

  for (int t = 0; t < TLEN; ++t){
    const int dt = t & (TCHUNK-1);
    const int hb = (t & 1) * 1152;

    // x A-frag: 2 ds_read_b64 + zero for quads 1..3 (k=4..7 are zero)
    uint2_t xh2 = *(const uint2_t*)&HS[XPH + (dt*16 + lid)*4];
    uint2_t xl2 = *(const uint2_t*)&HS[XPL + (dt*16 + lid)*4];
    xh2 = (q == 0) ? xh2 : (uint2_t)0;
    xl2 = (q == 0) ? xl2 : (uint2_t)0;
    union U8 { unsigned u[4]; bf16x8 v; };
    U8 uxh; uxh.u[0]=xh2[0]; uxh.u[1]=xh2[1]; uxh.u[2]=0u; uxh.u[3]=0u;
    U8 uxl; uxl.u[0]=xl2[0]; uxl.u[1]=xl2[1]; uxl.u[2]=0u; uxl.u[3]=0u;
    const bf16x8 xah = uxh.v, xal = uxl.v;

    // gate preacts: two accumulator chains per tile (latency overlap)
    float4_t g4[4];
    #pragma unroll
    for (int tl = 0; tl < 4; tl++){
      float4_t accA = {0.f,0.f,0.f,0.f};
      float4_t accB = {0.f,0.f,0.f,0.f};
      accA = MFMA(ah[0], Bh[tl][0], accA);
      accA = MFMA(ah[1], Bh[tl][1], accA);
      accA = MFMA(al[0], Bh[tl][0], accA);
      accA = MFMA(al[1], Bh[tl][1], accA);
      accB = MFMA(ah[0], Bl[tl][0], accB);
      accB = MFMA(ah[1], Bl[tl][1], accB);
      accB = MFMA(xah,   Xh[tl],    accB);
      accB = MFMA(xal,   Xh[tl],    accB);
      accB = MFMA(xah,   Xl[tl],    accB);
      g4[tl] = accA + accB;
    }

    // lane-local activations + c/h update; PRODUCER-SIDE trunc-split of h
    #pragma unroll
    for (int r = 0; r < 4; r++){
      const float ig = sigm (g4[0][r]);
      const float fg = sigm (g4[1][r]);
      const float gg = tanh_(g4[2][r]);
      const float og = sigm (g4[3][r]);
      creg[r] = fg*creg[r] + ig*gg;
      const float h = og * tanh_(creg[r]);
      const unsigned u  = __float_as_uint(h);
      const float    lf = h - __uint_as_float(u & 0xFFFF0000u);   // exact
      const int m = q*4 + r;
      HS[HHI + hb + m*72 + cw] = (unsigned short)(u >> 16);
      HS[HLO + hb + m*72 + cw] = (unsigned short)(__float_as_uint(lf) >> 16);
    }
    __syncthreads();   // the ONE barrier per step

    // rebuild h A-frags: 4 raw ds_read_b128, zero VALU
    {
      const unsigned short* ph = &HS[HHI + hb + lid*72 + q*8];
      const unsigned short* pl = &HS[HLO + hb + lid*72 + q*8];
      ah[0] = *(const bf16x8*)&ph[0];
      ah[1] = *(const bf16x8*)&ph[32];
      al[0] = *(const bf16x8*)&pl[0];
      al[1] = *(const bf16x8*)&pl[32];
    }

    // decoder on wave 0: out_t = h_t @ W_dec^T + b_dec  -> OOF staging
    if (w == 0){
      float4_t d = {0.f,0.f,0.f,0.f};
      d = MFMA(ah[0], Dh[0], d);
      d = MFMA(ah[1], Dh[1], d);
      d = MFMA(al[0], Dh[0], d);
      d = MFMA(al[1], Dh[1], d);
      d = MFMA(ah[0], Dl[0], d);
      d = MFMA(ah[1], Dl[1], d);
      if (lid < 3){
        #pragma unroll
        for (int r = 0; r < 4; r++)
          LF[OOF + (q*4+r)*196 + dt*3 + lid] = d[r] + bdec;
      }
    }

    // chunk boundary: flush out, stage+pack next x chunk
    if (dt == TCHUNK-1){
      __syncthreads();
      const int t0 = t - (TCHUNK-1);
      #pragma unroll
      for (int s = 0; s < 3; s++){
        const int f = tid + 256*s; const int row = f/48; const int off = (f%48)*4;
        float4_t v = *(const float4_t*)&LF[OOF + row*196 + off];
        *(float4_t*)(out + (size_t)(b0+row)*1536 + t0*3 + off) = v;
      }
      if (t + 1 < TLEN){
        #pragma unroll
        for (int s = 0; s < 3; s++){
          const int f = tid + 256*s; const int row = f/48; const int off = (f%48)*4;
          float4_t v = *(const float4_t*)(x + (size_t)(b0+row)*1536 + (t+1)*3 + off);
          *(float4_t*)&LF[XOF + row*196 + off] = v;
        }
        __syncthreads();
        #pragma unroll
        for (int s = 0; s < 4; s++){
          const int p = tid + 256*s;
          const float* xp = &LF[XOF + (p & 15)*196 + (p >> 4)*3];
          const unsigned u0 = __float_as_uint(xp[0]);
          const unsigned u1 = __float_as_uint(xp[1]);
          const unsigned u2 = __float_as_uint(xp[2]);
          const float l0 = xp[0] - __uint_as_float(u0 & 0xFFFF0000u);
          const float l1 = xp[1] - __uint_as_float(u1 & 0xFFFF0000u);
          const float l2 = xp[2] - __uint_as_float(u2 & 0xFFFF0000u);
          uint2_t hi, lo;
          hi[0] = (u0 >> 16) | (u1 & 0xFFFF0000u);
          hi[1] = (u2 >> 16) | 0x3F800000u;
          lo[0] = (__float_as_uint(l0) >> 16) | (__float_as_uint(l1) & 0xFFFF0000u);
          lo[1] = (__float_as_uint(l2) >> 16);
          *(uint2_t*)&HS[XPH + p*4] = hi;
          *(uint2_t*)&HS[XPL + p*4] = lo;
        }
      }
      __syncthreads();
    }
  }
}

extern "C" void kernel_launch(void* const* d_in, const int* in_sizes, int n_in,
                              void* d_out, int out_size, void* d_ws, size_t ws_size,
                              hipStream_t stream)
{
  const float* x     = (const float*)d_in[0];
  const float* W_ih  = (const float*)d_in[1];
  const float* W_hh  = (const float*)d_in[2];
  const float* b_ih  = (const float*)d_in[3];
  const float* b_hh  = (const float*)d_in[4];
  const float* W_dec = (const float*)d_in[5];
  const float* b_dec = (const float*)d_in[6];
  float* out = (float*)d_out;

  const int B = in_sizes[0] / (TLEN * 3);   // 4096
  const int blocks = B / 16;                // 256
  hipLaunchKernelGGL(LSTMAnomalyDetector_kernel, dim3(blocks), dim3(256), 0, stream,
                     x, W_ih, W_hh, b_ih, b_hh, W_dec, b_dec, out);
}